// Round 1
// baseline (2155.011 us; speedup 1.0000x reference)
//
#include <hip/hip_runtime.h>
#include <hip/hip_bf16.h>
#include <math.h>

// Problem constants
constexpr int N_SEQ = 8192;
constexpr int D     = 512;
constexpr int NH    = 8;
constexpr int DHEAD = 64;
constexpr int FFDIM = 2048;
constexpr int LLMD  = 4096;
constexpr int NLAYER= 2;

// ---------------------------------------------------------------------------
// x_ws = x_in + sinusoidal PE   (4M elements)
// ---------------------------------------------------------------------------
__global__ __launch_bounds__(256) void add_pe_kernel(const float* __restrict__ xin,
                                                     float* __restrict__ xout) {
  int idx = blockIdx.x * 256 + threadIdx.x;      // < 8192*512 = 4M
  int d = idx & (D - 1);
  int n = idx >> 9;
  float freq = expf((float)(d & ~1) * (-9.210340371976184f / 512.0f)); // exp(-2i*ln(1e4)/D)
  float arg = (float)n * freq;
  float pe = (d & 1) ? cosf(arg) : sinf(arg);
  xout[idx] = xin[idx] + pe;
}

// ---------------------------------------------------------------------------
// LayerNorm: one block (256 thr) per row of 512
// ---------------------------------------------------------------------------
__global__ __launch_bounds__(256) void ln_kernel(const float* __restrict__ in,
                                                 float* __restrict__ out,
                                                 const float* __restrict__ g,
                                                 const float* __restrict__ b) {
  int row = blockIdx.x, t = threadIdx.x;
  float2 v = *(const float2*)&in[(size_t)row * D + t * 2];
  float s  = v.x + v.y;
  float sq = v.x * v.x + v.y * v.y;
#pragma unroll
  for (int o = 32; o > 0; o >>= 1) { s += __shfl_down(s, o); sq += __shfl_down(sq, o); }
  __shared__ float ss[4], ssq[4];
  if ((t & 63) == 0) { ss[t >> 6] = s; ssq[t >> 6] = sq; }
  __syncthreads();
  s  = ss[0] + ss[1] + ss[2] + ss[3];
  sq = ssq[0] + ssq[1] + ssq[2] + ssq[3];
  float mu  = s * (1.0f / D);
  float var = sq * (1.0f / D) - mu * mu;
  float rs  = rsqrtf(var + 1e-5f);
  float2 gg = *(const float2*)&g[t * 2];
  float2 bb = *(const float2*)&b[t * 2];
  float2 o2;
  o2.x = (v.x - mu) * rs * gg.x + bb.x;
  o2.y = (v.y - mu) * rs * gg.y + bb.y;
  *(float2*)&out[(size_t)row * D + t * 2] = o2;
}

// ---------------------------------------------------------------------------
// fp32 GEMM: C[M,N] = A[M,K] * B[K,N]  (B row-major [K][N])
// 128x128 tile, BK=16, 256 threads, 8x8 micro-tile.
// FLAGS: 1=bias, 2=exact GELU, 4=residual add (C = res + result)
// M,N multiples of 128; K multiple of 16.
// ---------------------------------------------------------------------------
template <int FLAGS>
__global__ __launch_bounds__(256) void gemm_kernel(const float* __restrict__ A,
                                                   const float* __restrict__ B,
                                                   const float* __restrict__ bias,
                                                   const float* __restrict__ res,
                                                   float* __restrict__ C,
                                                   int M, int N, int K) {
  __shared__ float As[16][132];   // transposed A tile: As[k][m], +4 pad (bank spread)
  __shared__ float Bs[16][128];
  const int tid = threadIdx.x;
  const int tx = tid & 15, ty = tid >> 4;
  const int bm = blockIdx.y * 128, bn = blockIdx.x * 128;
  float acc[8][8] = {};
  const int arow = tid >> 2, acol = (tid & 3) * 4;
  const int brow = tid >> 5, bcol = (tid & 31) * 4;
  for (int k0 = 0; k0 < K; k0 += 16) {
#pragma unroll
    for (int p = 0; p < 2; ++p) {
      int r = arow + p * 64;
      float4 a = *(const float4*)&A[(size_t)(bm + r) * K + (k0 + acol)];
      As[acol + 0][r] = a.x; As[acol + 1][r] = a.y;
      As[acol + 2][r] = a.z; As[acol + 3][r] = a.w;
    }
#pragma unroll
    for (int p = 0; p < 2; ++p) {
      int r = brow + p * 8;
      *(float4*)&Bs[r][bcol] = *(const float4*)&B[(size_t)(k0 + r) * N + (bn + bcol)];
    }
    __syncthreads();
#pragma unroll
    for (int kk = 0; kk < 16; ++kk) {
      float a[8], b[8];
      *(float4*)&a[0] = *(const float4*)&As[kk][ty * 8];
      *(float4*)&a[4] = *(const float4*)&As[kk][ty * 8 + 4];
      *(float4*)&b[0] = *(const float4*)&Bs[kk][tx * 8];
      *(float4*)&b[4] = *(const float4*)&Bs[kk][tx * 8 + 4];
#pragma unroll
      for (int i = 0; i < 8; ++i)
#pragma unroll
        for (int j = 0; j < 8; ++j)
          acc[i][j] = fmaf(a[i], b[j], acc[i][j]);
    }
    __syncthreads();
  }
#pragma unroll
  for (int i = 0; i < 8; ++i) {
    int row = bm + ty * 8 + i;
    float outv[8];
#pragma unroll
    for (int j = 0; j < 8; ++j) {
      int col = bn + tx * 8 + j;
      float v0 = acc[i][j];
      if (FLAGS & 1) v0 += bias[col];
      if (FLAGS & 2) v0 = 0.5f * v0 * (1.0f + erff(v0 * 0.7071067811865475f));
      outv[j] = v0;
    }
    if (FLAGS & 4) {
      float4 r0 = *(const float4*)&res[(size_t)row * N + bn + tx * 8];
      float4 r1 = *(const float4*)&res[(size_t)row * N + bn + tx * 8 + 4];
      outv[0] += r0.x; outv[1] += r0.y; outv[2] += r0.z; outv[3] += r0.w;
      outv[4] += r1.x; outv[5] += r1.y; outv[6] += r1.z; outv[7] += r1.w;
    }
    *(float4*)&C[(size_t)row * N + bn + tx * 8]     = *(float4*)&outv[0];
    *(float4*)&C[(size_t)row * N + bn + tx * 8 + 4] = *(float4*)&outv[4];
  }
}

// ---------------------------------------------------------------------------
// q softmax over feature dim (64 per head), *scale. One wave per (row,head).
// q layout [N, 512]: head h occupies cols h*64..h*64+63 -> flat wid*64+lane.
// ---------------------------------------------------------------------------
__global__ __launch_bounds__(256) void qsoftmax_kernel(float* __restrict__ q) {
  int gt = blockIdx.x * 256 + threadIdx.x;
  int wid = gt >> 6, lane = gt & 63;
  float v = q[(size_t)wid * 64 + lane];
  float m = v;
#pragma unroll
  for (int o = 32; o > 0; o >>= 1) m = fmaxf(m, __shfl_xor(m, o));
  float e = expf(v - m);
  float s = e;
#pragma unroll
  for (int o = 32; o > 0; o >>= 1) s += __shfl_xor(s, o);
  q[(size_t)wid * 64 + lane] = e / s * 0.125f;   // * DH^-0.5
}

// ---------------------------------------------------------------------------
// k softmax over sequence dim (8192) per column. One block per column.
// ---------------------------------------------------------------------------
__global__ __launch_bounds__(256) void ksoftmax_kernel(float* __restrict__ k) {
  int c = blockIdx.x, t = threadIdx.x;
  float vals[32];
  float m = -1e30f;
#pragma unroll
  for (int i = 0; i < 32; ++i) {
    vals[i] = k[(size_t)(i * 256 + t) * D + c];
    m = fmaxf(m, vals[i]);
  }
#pragma unroll
  for (int o = 32; o > 0; o >>= 1) m = fmaxf(m, __shfl_xor(m, o));
  __shared__ float sm[4];
  if ((t & 63) == 0) sm[t >> 6] = m;
  __syncthreads();
  m = fmaxf(fmaxf(sm[0], sm[1]), fmaxf(sm[2], sm[3]));
  float s = 0.f;
#pragma unroll
  for (int i = 0; i < 32; ++i) { vals[i] = expf(vals[i] - m); s += vals[i]; }
#pragma unroll
  for (int o = 32; o > 0; o >>= 1) s += __shfl_xor(s, o);
  __shared__ float ssum[4];
  if ((t & 63) == 0) ssum[t >> 6] = s;
  __syncthreads();
  s = ssum[0] + ssum[1] + ssum[2] + ssum[3];
  float inv = 1.0f / s;
#pragma unroll
  for (int i = 0; i < 32; ++i) k[(size_t)(i * 256 + t) * D + c] = vals[i] * inv;
}

// ---------------------------------------------------------------------------
// ctx partials: ctx[h][d][e] = sum_n k[n,h*64+d]*v[n,h*64+e], split-K over 32
// chunks of 256 rows. grid (32, 8). Deterministic (no atomics).
// ---------------------------------------------------------------------------
__global__ __launch_bounds__(256) void ctx_partial_kernel(const float* __restrict__ k,
                                                          const float* __restrict__ v,
                                                          float* __restrict__ part) {
  int chunk = blockIdx.x, h = blockIdx.y, t = threadIdx.x;
  __shared__ float ks[64][64], vs[64][64];
  float acc[16] = {};
  int e0 = (t >> 6) * 16, dd = t & 63;
  for (int s0 = 0; s0 < 256; s0 += 64) {
    size_t rowbase = (size_t)chunk * 256 + s0;
    __syncthreads();
    for (int i = t; i < 1024; i += 256) {
      int r = i >> 4, c4 = (i & 15) * 4;
      *(float4*)&ks[r][c4] = *(const float4*)&k[(rowbase + r) * D + h * 64 + c4];
      *(float4*)&vs[r][c4] = *(const float4*)&v[(rowbase + r) * D + h * 64 + c4];
    }
    __syncthreads();
    for (int r = 0; r < 64; ++r) {
      float kd = ks[r][dd];
      float4 v0 = *(const float4*)&vs[r][e0];
      float4 v1 = *(const float4*)&vs[r][e0 + 4];
      float4 v2 = *(const float4*)&vs[r][e0 + 8];
      float4 v3 = *(const float4*)&vs[r][e0 + 12];
      acc[0]  = fmaf(kd, v0.x, acc[0]);  acc[1]  = fmaf(kd, v0.y, acc[1]);
      acc[2]  = fmaf(kd, v0.z, acc[2]);  acc[3]  = fmaf(kd, v0.w, acc[3]);
      acc[4]  = fmaf(kd, v1.x, acc[4]);  acc[5]  = fmaf(kd, v1.y, acc[5]);
      acc[6]  = fmaf(kd, v1.z, acc[6]);  acc[7]  = fmaf(kd, v1.w, acc[7]);
      acc[8]  = fmaf(kd, v2.x, acc[8]);  acc[9]  = fmaf(kd, v2.y, acc[9]);
      acc[10] = fmaf(kd, v2.z, acc[10]); acc[11] = fmaf(kd, v2.w, acc[11]);
      acc[12] = fmaf(kd, v3.x, acc[12]); acc[13] = fmaf(kd, v3.y, acc[13]);
      acc[14] = fmaf(kd, v3.z, acc[14]); acc[15] = fmaf(kd, v3.w, acc[15]);
    }
  }
  float* pb = &part[((size_t)h * 32 + chunk) * 4096 + dd * 64 + e0];
#pragma unroll
  for (int j = 0; j < 16; ++j) pb[j] = acc[j];
}

__global__ __launch_bounds__(256) void ctx_reduce_kernel(const float* __restrict__ part,
                                                         float* __restrict__ ctx) {
  int idx = blockIdx.x * 256 + threadIdx.x;   // < 8*4096
  int h = idx >> 12, de = idx & 4095;
  float s = 0.f;
#pragma unroll 8
  for (int c = 0; c < 32; ++c) s += part[((size_t)h * 32 + c) * 4096 + de];
  ctx[(size_t)h * 4096 + de] = s;
}

// ---------------------------------------------------------------------------
// o[n, h*64+e] = sum_d q[n,h*64+d] * ctx[h][d][e].  grid (256 rowchunks, 8).
// ---------------------------------------------------------------------------
__global__ __launch_bounds__(256) void attn_o_kernel(const float* __restrict__ q,
                                                     const float* __restrict__ ctx,
                                                     float* __restrict__ o) {
  int h = blockIdx.y, rc = blockIdx.x, t = threadIdx.x;
  __shared__ float cs[64][64];
  __shared__ float qs[32][64];
  for (int i = t; i < 1024; i += 256) {
    int dd = i >> 4, c4 = (i & 15) * 4;
    *(float4*)&cs[dd][c4] = *(const float4*)&ctx[(size_t)h * 4096 + dd * 64 + c4];
  }
  int rowbase = rc * 32;
  for (int i = t; i < 512; i += 256) {
    int r = i >> 4, c4 = (i & 15) * 4;
    *(float4*)&qs[r][c4] = *(const float4*)&q[(size_t)(rowbase + r) * D + h * 64 + c4];
  }
  __syncthreads();
  int e = t & 63, r0 = (t >> 6) * 8;
  float accv[8] = {};
  for (int dd = 0; dd < 64; ++dd) {
    float ce = cs[dd][e];
#pragma unroll
    for (int i = 0; i < 8; ++i) accv[i] = fmaf(qs[r0 + i][dd], ce, accv[i]);
  }
#pragma unroll
  for (int i = 0; i < 8; ++i)
    o[(size_t)(rowbase + r0 + i) * D + h * 64 + e] = accv[i];
}

// ---------------------------------------------------------------------------
extern "C" void kernel_launch(void* const* d_in, const int* in_sizes, int n_in,
                              void* d_out, int out_size, void* d_ws, size_t ws_size,
                              hipStream_t stream) {
  const float* x_in  = (const float*)d_in[0];
  const float* ln1_g = (const float*)d_in[1];
  const float* ln1_b = (const float*)d_in[2];
  const float* Wq    = (const float*)d_in[3];
  const float* Wk    = (const float*)d_in[4];
  const float* Wv    = (const float*)d_in[5];
  const float* Wo    = (const float*)d_in[6];
  const float* bo    = (const float*)d_in[7];
  const float* ln2_g = (const float*)d_in[8];
  const float* ln2_b = (const float*)d_in[9];
  const float* W1    = (const float*)d_in[10];
  const float* b1    = (const float*)d_in[11];
  const float* W2    = (const float*)d_in[12];
  const float* b2    = (const float*)d_in[13];
  const float* projW = (const float*)d_in[14];
  const float* projb = (const float*)d_in[15];
  float* out = (float*)d_out;
  float* ws  = (float*)d_ws;

  // workspace layout (floats); FFH deliberately overlaps Q..O (disjoint phases)
  float* X    = ws;                               // 4M  floats
  float* Hb   = ws + (size_t)4 * 1024 * 1024;     // 4M
  float* Q    = ws + (size_t)8 * 1024 * 1024;     // 4M
  float* Kb   = ws + (size_t)12 * 1024 * 1024;    // 4M
  float* V    = ws + (size_t)16 * 1024 * 1024;    // 4M
  float* O    = ws + (size_t)20 * 1024 * 1024;    // 4M
  float* FFH  = ws + (size_t)8 * 1024 * 1024;     // 16M (overlaps Q..O)
  float* CTX  = ws + (size_t)24 * 1024 * 1024;    // 32K
  float* CTXP = CTX + NH * DHEAD * DHEAD;         // 1M

  add_pe_kernel<<<(N_SEQ * D) / 256, 256, 0, stream>>>(x_in, X);

  dim3 g512(512 / 128, N_SEQ / 128);
  dim3 gff1(FFDIM / 128, N_SEQ / 128);
  dim3 gproj(LLMD / 128, N_SEQ / 128);

  for (int l = 0; l < NLAYER; ++l) {
    ln_kernel<<<N_SEQ, 256, 0, stream>>>(X, Hb, ln1_g + l * D, ln1_b + l * D);
    gemm_kernel<0><<<g512, 256, 0, stream>>>(Hb, Wq + (size_t)l * D * D, nullptr, nullptr, Q, N_SEQ, 512, 512);
    gemm_kernel<0><<<g512, 256, 0, stream>>>(Hb, Wk + (size_t)l * D * D, nullptr, nullptr, Kb, N_SEQ, 512, 512);
    gemm_kernel<0><<<g512, 256, 0, stream>>>(Hb, Wv + (size_t)l * D * D, nullptr, nullptr, V, N_SEQ, 512, 512);
    qsoftmax_kernel<<<(N_SEQ * NH * 64) / 256, 256, 0, stream>>>(Q);
    ksoftmax_kernel<<<D, 256, 0, stream>>>(Kb);
    dim3 gctx(32, NH);
    ctx_partial_kernel<<<gctx, 256, 0, stream>>>(Kb, V, CTXP);
    ctx_reduce_kernel<<<(NH * DHEAD * DHEAD) / 256, 256, 0, stream>>>(CTXP, CTX);
    dim3 go(N_SEQ / 32, NH);
    attn_o_kernel<<<go, 256, 0, stream>>>(Q, CTX, O);
    gemm_kernel<5><<<g512, 256, 0, stream>>>(O, Wo + (size_t)l * D * D, bo + l * D, X, X, N_SEQ, 512, 512);
    ln_kernel<<<N_SEQ, 256, 0, stream>>>(X, Hb, ln2_g + l * D, ln2_b + l * D);
    gemm_kernel<3><<<gff1, 256, 0, stream>>>(Hb, W1 + (size_t)l * D * FFDIM, b1 + l * FFDIM, nullptr, FFH, N_SEQ, FFDIM, 512);
    gemm_kernel<5><<<g512, 256, 0, stream>>>(FFH, W2 + (size_t)l * FFDIM * D, b2 + l * D, X, X, N_SEQ, 512, FFDIM);
  }
  gemm_kernel<1><<<gproj, 256, 0, stream>>>(X, projW, projb, nullptr, out, N_SEQ, LLMD, 512);
}

// Round 2
// 629.255 us; speedup vs baseline: 3.4247x; 3.4247x over previous
//
#include <hip/hip_runtime.h>
#include <hip/hip_bf16.h>
#include <math.h>

constexpr int N_SEQ = 8192;
constexpr int D     = 512;
constexpr int NH    = 8;
constexpr int FFDIM = 2048;
constexpr int LLMD  = 4096;
constexpr int NLAYER= 2;

typedef __bf16 bf16x8 __attribute__((ext_vector_type(8)));
typedef float  f32x4  __attribute__((ext_vector_type(4)));
typedef unsigned short u16x8 __attribute__((ext_vector_type(8)));

__device__ __forceinline__ unsigned short f2bf(float x) {
  unsigned u = __builtin_bit_cast(unsigned, x);
  unsigned r = (u + 0x7FFFu + ((u >> 16) & 1u)) >> 16;
  return (unsigned short)r;
}

// async global->LDS, 16B per lane (wave-uniform LDS base + lane*16)
#define GLOAD16(g, l)                                                        \
  __builtin_amdgcn_global_load_lds(                                          \
      (const __attribute__((address_space(1))) void*)(g),                    \
      (__attribute__((address_space(3))) void*)(l), 16, 0, 0)

// ---------------------------------------------------------------------------
// x_ws = x_in + sinusoidal PE
// ---------------------------------------------------------------------------
__global__ __launch_bounds__(256) void add_pe_kernel(const float* __restrict__ xin,
                                                     float* __restrict__ xout) {
  int idx = blockIdx.x * 256 + threadIdx.x;
  int d = idx & (D - 1);
  int n = idx >> 9;
  float freq = expf((float)(d & ~1) * (-9.210340371976184f / 512.0f));
  float arg = (float)n * freq;
  float pe = (d & 1) ? cosf(arg) : sinf(arg);
  xout[idx] = xin[idx] + pe;
}

// ---------------------------------------------------------------------------
// LayerNorm: one wave per row of 512; bf16 output
// ---------------------------------------------------------------------------
__global__ __launch_bounds__(256) void ln_bf16(const float* __restrict__ in,
                                               unsigned short* __restrict__ out,
                                               const float* __restrict__ g,
                                               const float* __restrict__ b) {
  int row  = (blockIdx.x * 256 + threadIdx.x) >> 6;
  int lane = threadIdx.x & 63;
  const float* p = in + (size_t)row * D + lane * 8;
  f32x4 v0 = *(const f32x4*)p;
  f32x4 v1 = *(const f32x4*)(p + 4);
  float s  = v0[0] + v0[1] + v0[2] + v0[3] + v1[0] + v1[1] + v1[2] + v1[3];
  float sq = v0[0]*v0[0] + v0[1]*v0[1] + v0[2]*v0[2] + v0[3]*v0[3]
           + v1[0]*v1[0] + v1[1]*v1[1] + v1[2]*v1[2] + v1[3]*v1[3];
#pragma unroll
  for (int o = 32; o > 0; o >>= 1) { s += __shfl_xor(s, o); sq += __shfl_xor(sq, o); }
  float mu  = s * (1.0f / D);
  float var = sq * (1.0f / D) - mu * mu;
  float rs  = rsqrtf(var + 1e-5f);
  f32x4 g0 = *(const f32x4*)(g + lane * 8);
  f32x4 g1 = *(const f32x4*)(g + lane * 8 + 4);
  f32x4 b0 = *(const f32x4*)(b + lane * 8);
  f32x4 b1 = *(const f32x4*)(b + lane * 8 + 4);
  u16x8 r;
#pragma unroll
  for (int i = 0; i < 4; ++i) r[i]     = f2bf((v0[i] - mu) * rs * g0[i] + b0[i]);
#pragma unroll
  for (int i = 0; i < 4; ++i) r[i + 4] = f2bf((v1[i] - mu) * rs * g1[i] + b1[i]);
  *(u16x8*)(out + (size_t)row * D + lane * 8) = r;
}

// ---------------------------------------------------------------------------
// Weight convert fp32 [K][N] -> bf16 transposed [N][K]
// ---------------------------------------------------------------------------
__global__ __launch_bounds__(256) void wconv1(const float* __restrict__ W,
                                              unsigned short* __restrict__ Wt,
                                              int K, int N) {
  __shared__ float s[32][33];
  int bk = blockIdx.x * 32, bn = blockIdx.y * 32;
  int r = threadIdx.x >> 5, c = threadIdx.x & 31;
#pragma unroll
  for (int i = 0; i < 4; ++i)
    s[r + 8 * i][c] = W[(size_t)(bk + r + 8 * i) * N + bn + c];
  __syncthreads();
#pragma unroll
  for (int i = 0; i < 4; ++i) {
    int rr = r + 8 * i;
    Wt[(size_t)(bn + rr) * K + bk + c] = f2bf(s[c][rr]);
  }
}

__global__ __launch_bounds__(256) void wconv4(const float* __restrict__ W0,
                                              const float* __restrict__ W1,
                                              const float* __restrict__ W2,
                                              const float* __restrict__ W3,
                                              unsigned short* __restrict__ dst,
                                              int K, int N) {
  const float* W = (blockIdx.z == 0) ? W0 : (blockIdx.z == 1) ? W1
                 : (blockIdx.z == 2) ? W2 : W3;
  unsigned short* Wt = dst + (size_t)blockIdx.z * K * N;
  __shared__ float s[32][33];
  int bk = blockIdx.x * 32, bn = blockIdx.y * 32;
  int r = threadIdx.x >> 5, c = threadIdx.x & 31;
#pragma unroll
  for (int i = 0; i < 4; ++i)
    s[r + 8 * i][c] = W[(size_t)(bk + r + 8 * i) * N + bn + c];
  __syncthreads();
#pragma unroll
  for (int i = 0; i < 4; ++i) {
    int rr = r + 8 * i;
    Wt[(size_t)(bn + rr) * K + bk + c] = f2bf(s[c][rr]);
  }
}

// ---------------------------------------------------------------------------
// bf16 MFMA GEMM (m97 structure): C[M,N] = A[M,K] * Bt[N,K]^T
// 128x128 tile, BK=32, 256 thr = 4 waves (2x2), each wave 64x64 via 4x4
// mfma_f32_16x16x32_bf16 fragments.
// FLAGS: 1=bias, 2=exact GELU, 4=residual(res fp32), 8=write bf16 Cb,
//        16=skip fp32 C write
// ---------------------------------------------------------------------------
template <int FLAGS>
__global__ __launch_bounds__(256) void mgemm(const unsigned short* __restrict__ A,
                                             const unsigned short* __restrict__ Bt,
                                             const float* __restrict__ bias,
                                             const float* __restrict__ res,
                                             float* __restrict__ C,
                                             unsigned short* __restrict__ Cb,
                                             int M, int N, int K) {
  __shared__ unsigned short As[128][32];
  __shared__ unsigned short Bs[128][32];
  const int tid  = threadIdx.x;
  const int lane = tid & 63, wv = tid >> 6;
  const int bm = blockIdx.y * 128, bn = blockIdx.x * 128;
  const int wr = (wv >> 1) * 64, wc = (wv & 1) * 64;

  f32x4 acc[4][4] = {};

  // staging: wave wv loads rows [wv*32, wv*32+32) of both tiles
  const int srow = wv * 32 + (lane >> 2);
  const int scol = (lane & 3) * 8;
  const unsigned short* Ap0 = A  + (size_t)(bm + srow) * K + scol;
  const unsigned short* Ap1 = Ap0 + (size_t)16 * K;
  const unsigned short* Bp0 = Bt + (size_t)(bn + srow) * K + scol;
  const unsigned short* Bp1 = Bp0 + (size_t)16 * K;
  unsigned short* Al0 = &As[srow][scol];
  unsigned short* Al1 = &As[srow + 16][scol];
  unsigned short* Bl0 = &Bs[srow][scol];
  unsigned short* Bl1 = &Bs[srow + 16][scol];

  const int kh = (lane >> 4) * 8;   // k-offset of this lane's fragment
  const int fr = lane & 15;         // row (A) / col (B) within 16x16 frag

  for (int k0 = 0; k0 < K; k0 += 32) {
    GLOAD16(Ap0 + k0, Al0);
    GLOAD16(Ap1 + k0, Al1);
    GLOAD16(Bp0 + k0, Bl0);
    GLOAD16(Bp1 + k0, Bl1);
    __syncthreads();
    bf16x8 af[4], bfv[4];
#pragma unroll
    for (int mi = 0; mi < 4; ++mi)
      af[mi] = *(const bf16x8*)&As[wr + mi * 16 + fr][kh];
#pragma unroll
    for (int ni = 0; ni < 4; ++ni)
      bfv[ni] = *(const bf16x8*)&Bs[wc + ni * 16 + fr][kh];
#pragma unroll
    for (int mi = 0; mi < 4; ++mi)
#pragma unroll
      for (int ni = 0; ni < 4; ++ni)
        acc[mi][ni] = __builtin_amdgcn_mfma_f32_16x16x32_bf16(af[mi], bfv[ni], acc[mi][ni], 0, 0, 0);
    __syncthreads();
  }

  // epilogue: lane holds D[(lane>>4)*4+j][lane&15] per fragment
  const int r4 = (lane >> 4) * 4, cc = lane & 15;
#pragma unroll
  for (int mi = 0; mi < 4; ++mi) {
#pragma unroll
    for (int ni = 0; ni < 4; ++ni) {
      int col = bn + wc + ni * 16 + cc;
      float bsv = (FLAGS & 1) ? bias[col] : 0.0f;
      f32x4 v = acc[mi][ni];
#pragma unroll
      for (int j = 0; j < 4; ++j) {
        int row = bm + wr + mi * 16 + r4 + j;
        float x = v[j] + bsv;
        if (FLAGS & 2) x = 0.5f * x * (1.0f + erff(x * 0.7071067811865475f));
        if (FLAGS & 4) x += res[(size_t)row * N + col];
        if (!(FLAGS & 16)) C[(size_t)row * N + col] = x;
        if (FLAGS & 8) Cb[(size_t)row * N + col] = f2bf(x);
      }
    }
  }
}

// ---------------------------------------------------------------------------
// q softmax over feature dim (64 per head), *scale. One wave per (row,head).
// ---------------------------------------------------------------------------
__global__ __launch_bounds__(256) void qsoftmax_kernel(float* __restrict__ q) {
  int gt = blockIdx.x * 256 + threadIdx.x;
  int wid = gt >> 6, lane = gt & 63;
  float v = q[(size_t)wid * 64 + lane];
  float m = v;
#pragma unroll
  for (int o = 32; o > 0; o >>= 1) m = fmaxf(m, __shfl_xor(m, o));
  float e = __expf(v - m);
  float s = e;
#pragma unroll
  for (int o = 32; o > 0; o >>= 1) s += __shfl_xor(s, o);
  q[(size_t)wid * 64 + lane] = e / s * 0.125f;
}

// ---------------------------------------------------------------------------
// k softmax over sequence dim, coalesced 3-phase
// ---------------------------------------------------------------------------
__global__ __launch_bounds__(512) void ksm_partial(const float* __restrict__ k,
                                                   float* __restrict__ pm,
                                                   float* __restrict__ ps) {
  int c = threadIdx.x, b = blockIdx.x;
  const float* p = k + (size_t)b * 256 * D + c;
  float m = -1e30f, s = 0.f;
  for (int r = 0; r < 256; ++r) {
    float v = p[(size_t)r * D];
    float nm = fmaxf(m, v);
    s = s * __expf(m - nm) + __expf(v - nm);
    m = nm;
  }
  pm[b * D + c] = m;
  ps[b * D + c] = s;
}

__global__ __launch_bounds__(512) void ksm_merge(const float* __restrict__ pm,
                                                 const float* __restrict__ ps,
                                                 float* __restrict__ cm,
                                                 float* __restrict__ ci) {
  int c = threadIdx.x;
  float m = -1e30f;
  for (int b = 0; b < 32; ++b) m = fmaxf(m, pm[b * D + c]);
  float s = 0.f;
  for (int b = 0; b < 32; ++b) s += ps[b * D + c] * __expf(pm[b * D + c] - m);
  cm[c] = m;
  ci[c] = 1.0f / s;
}

__global__ __launch_bounds__(256) void ksm_norm(float* __restrict__ k,
                                                const float* __restrict__ cm,
                                                const float* __restrict__ ci) {
  int idx = blockIdx.x * 256 + threadIdx.x;
  int c = idx & (D - 1);
  k[idx] = __expf(k[idx] - cm[c]) * ci[c];
}

// ---------------------------------------------------------------------------
// ctx partials + reduce (fp32)
// ---------------------------------------------------------------------------
__global__ __launch_bounds__(256) void ctx_partial_kernel(const float* __restrict__ k,
                                                          const float* __restrict__ v,
                                                          float* __restrict__ part) {
  int chunk = blockIdx.x, h = blockIdx.y, t = threadIdx.x;
  __shared__ float ks[64][64], vs[64][64];
  float acc[16] = {};
  int e0 = (t >> 6) * 16, dd = t & 63;
  for (int s0 = 0; s0 < 256; s0 += 64) {
    size_t rowbase = (size_t)chunk * 256 + s0;
    __syncthreads();
    for (int i = t; i < 1024; i += 256) {
      int r = i >> 4, c4 = (i & 15) * 4;
      *(float4*)&ks[r][c4] = *(const float4*)&k[(rowbase + r) * D + h * 64 + c4];
      *(float4*)&vs[r][c4] = *(const float4*)&v[(rowbase + r) * D + h * 64 + c4];
    }
    __syncthreads();
    for (int r = 0; r < 64; ++r) {
      float kd = ks[r][dd];
      float4 v0 = *(const float4*)&vs[r][e0];
      float4 v1 = *(const float4*)&vs[r][e0 + 4];
      float4 v2 = *(const float4*)&vs[r][e0 + 8];
      float4 v3 = *(const float4*)&vs[r][e0 + 12];
      acc[0]  = fmaf(kd, v0.x, acc[0]);  acc[1]  = fmaf(kd, v0.y, acc[1]);
      acc[2]  = fmaf(kd, v0.z, acc[2]);  acc[3]  = fmaf(kd, v0.w, acc[3]);
      acc[4]  = fmaf(kd, v1.x, acc[4]);  acc[5]  = fmaf(kd, v1.y, acc[5]);
      acc[6]  = fmaf(kd, v1.z, acc[6]);  acc[7]  = fmaf(kd, v1.w, acc[7]);
      acc[8]  = fmaf(kd, v2.x, acc[8]);  acc[9]  = fmaf(kd, v2.y, acc[9]);
      acc[10] = fmaf(kd, v2.z, acc[10]); acc[11] = fmaf(kd, v2.w, acc[11]);
      acc[12] = fmaf(kd, v3.x, acc[12]); acc[13] = fmaf(kd, v3.y, acc[13]);
      acc[14] = fmaf(kd, v3.z, acc[14]); acc[15] = fmaf(kd, v3.w, acc[15]);
    }
  }
  float* pb = &part[((size_t)h * 32 + chunk) * 4096 + dd * 64 + e0];
#pragma unroll
  for (int j = 0; j < 16; ++j) pb[j] = acc[j];
}

__global__ __launch_bounds__(256) void ctx_reduce_kernel(const float* __restrict__ part,
                                                         float* __restrict__ ctx) {
  int idx = blockIdx.x * 256 + threadIdx.x;
  int h = idx >> 12, de = idx & 4095;
  float s = 0.f;
#pragma unroll 8
  for (int c = 0; c < 32; ++c) s += part[((size_t)h * 32 + c) * 4096 + de];
  ctx[(size_t)h * 4096 + de] = s;
}

// ---------------------------------------------------------------------------
// o[n, h*64+e] = sum_d q[n,h*64+d] * ctx[h][d][e]  (bf16 output)
// ---------------------------------------------------------------------------
__global__ __launch_bounds__(256) void attn_o_kernel(const float* __restrict__ q,
                                                     const float* __restrict__ ctx,
                                                     unsigned short* __restrict__ o) {
  int h = blockIdx.y, rc = blockIdx.x, t = threadIdx.x;
  __shared__ float cs[64][64];
  __shared__ float qs[32][64];
  for (int i = t; i < 1024; i += 256) {
    int dd = i >> 4, c4 = (i & 15) * 4;
    *(float4*)&cs[dd][c4] = *(const float4*)&ctx[(size_t)h * 4096 + dd * 64 + c4];
  }
  int rowbase = rc * 32;
  for (int i = t; i < 512; i += 256) {
    int r = i >> 4, c4 = (i & 15) * 4;
    *(float4*)&qs[r][c4] = *(const float4*)&q[(size_t)(rowbase + r) * D + h * 64 + c4];
  }
  __syncthreads();
  int e = t & 63, r0 = (t >> 6) * 8;
  float accv[8] = {};
  for (int dd = 0; dd < 64; ++dd) {
    float ce = cs[dd][e];
#pragma unroll
    for (int i = 0; i < 8; ++i) accv[i] = fmaf(qs[r0 + i][dd], ce, accv[i]);
  }
#pragma unroll
  for (int i = 0; i < 8; ++i)
    o[(size_t)(rowbase + r0 + i) * D + h * 64 + e] = f2bf(accv[i]);
}

// ---------------------------------------------------------------------------
extern "C" void kernel_launch(void* const* d_in, const int* in_sizes, int n_in,
                              void* d_out, int out_size, void* d_ws, size_t ws_size,
                              hipStream_t stream) {
  const float* x_in  = (const float*)d_in[0];
  const float* ln1_g = (const float*)d_in[1];
  const float* ln1_b = (const float*)d_in[2];
  const float* Wq    = (const float*)d_in[3];
  const float* Wk    = (const float*)d_in[4];
  const float* Wv    = (const float*)d_in[5];
  const float* Wo    = (const float*)d_in[6];
  const float* bo    = (const float*)d_in[7];
  const float* ln2_g = (const float*)d_in[8];
  const float* ln2_b = (const float*)d_in[9];
  const float* W1    = (const float*)d_in[10];
  const float* b1    = (const float*)d_in[11];
  const float* W2    = (const float*)d_in[12];
  const float* b2    = (const float*)d_in[13];
  const float* projW = (const float*)d_in[14];
  const float* projb = (const float*)d_in[15];
  float* out = (float*)d_out;
  float* ws  = (float*)d_ws;
  constexpr size_t M1 = 1u << 20;

  // fp32 region
  float* X    = ws;                    // [0,16MB)
  float* Q    = ws + 4 * M1;           // [16,32)
  float* Kb   = ws + 8 * M1;           // [32,48)
  float* V    = ws + 12 * M1;          // [48,64)
  float* CTX  = ws + 16 * M1;          // 128KB
  float* CTXP = CTX + 32768;           // 4MB
  float* PM   = CTXP + M1;             // 64KB
  float* PS   = PM + 16384;            // 64KB
  float* CMAX = PS + 16384;            // 2KB
  float* CINV = CMAX + 512;            // 2KB
  // bf16 region
  unsigned short* Hb  = (unsigned short*)(ws + 18 * M1);  // [72,80)MB
  unsigned short* O   = (unsigned short*)(ws + 20 * M1);  // [80,88)MB
  unsigned short* Xb  = O;                                // proj input (after O dead)
  unsigned short* FFH = (unsigned short*)Q;               // [16,48)MB overlaps Q,Kb
  unsigned short* WtQKVO = (unsigned short*)(ws + 22 * M1); // 2MB  (4x 512x512)
  unsigned short* W1T    = WtQKVO + M1;                     // 2MB  [2048][512]
  unsigned short* W2T    = W1T + M1;                        // 2MB  [512][2048]
  unsigned short* PRT    = W2T + M1;                        // 4MB  [4096][512]

  add_pe_kernel<<<(N_SEQ * D) / 256, 256, 0, stream>>>(x_in, X);
  wconv1<<<dim3(16, 128), 256, 0, stream>>>(projW, PRT, 512, LLMD);

  dim3 g512(512 / 128, N_SEQ / 128);
  dim3 gff1(FFDIM / 128, N_SEQ / 128);
  dim3 gproj(LLMD / 128, N_SEQ / 128);

  for (int l = 0; l < NLAYER; ++l) {
    size_t DD = (size_t)D * D, DF = (size_t)D * FFDIM;
    wconv4<<<dim3(16, 16, 4), 256, 0, stream>>>(Wq + l * DD, Wk + l * DD,
                                                Wv + l * DD, Wo + l * DD,
                                                WtQKVO, 512, 512);
    wconv1<<<dim3(16, 64), 256, 0, stream>>>(W1 + l * DF, W1T, 512, FFDIM);
    wconv1<<<dim3(64, 16), 256, 0, stream>>>(W2 + l * DF, W2T, FFDIM, 512);

    ln_bf16<<<N_SEQ / 4, 256, 0, stream>>>(X, Hb, ln1_g + l * D, ln1_b + l * D);
    mgemm<0><<<g512, 256, 0, stream>>>(Hb, WtQKVO,            nullptr, nullptr, Q,  nullptr, N_SEQ, 512, 512);
    mgemm<0><<<g512, 256, 0, stream>>>(Hb, WtQKVO + 262144,   nullptr, nullptr, Kb, nullptr, N_SEQ, 512, 512);
    mgemm<0><<<g512, 256, 0, stream>>>(Hb, WtQKVO + 524288,   nullptr, nullptr, V,  nullptr, N_SEQ, 512, 512);
    qsoftmax_kernel<<<(N_SEQ * D) / 256, 256, 0, stream>>>(Q);
    ksm_partial<<<32, 512, 0, stream>>>(Kb, PM, PS);
    ksm_merge<<<1, 512, 0, stream>>>(PM, PS, CMAX, CINV);
    ksm_norm<<<(N_SEQ * D) / 256, 256, 0, stream>>>(Kb, CMAX, CINV);
    ctx_partial_kernel<<<dim3(32, NH), 256, 0, stream>>>(Kb, V, CTXP);
    ctx_reduce_kernel<<<(NH * 4096) / 256, 256, 0, stream>>>(CTXP, CTX);
    attn_o_kernel<<<dim3(N_SEQ / 32, NH), 256, 0, stream>>>(Q, CTX, O);
    mgemm<5><<<g512, 256, 0, stream>>>(O, WtQKVO + 786432, bo + l * D, X, X, nullptr, N_SEQ, 512, 512);
    ln_bf16<<<N_SEQ / 4, 256, 0, stream>>>(X, Hb, ln2_g + l * D, ln2_b + l * D);
    mgemm<27><<<gff1, 256, 0, stream>>>(Hb, W1T, b1 + l * FFDIM, nullptr, nullptr, FFH, N_SEQ, FFDIM, 512);
    if (l == NLAYER - 1)
      mgemm<13><<<g512, 256, 0, stream>>>(FFH, W2T, b2 + l * D, X, X, Xb, N_SEQ, 512, FFDIM);
    else
      mgemm<5><<<g512, 256, 0, stream>>>(FFH, W2T, b2 + l * D, X, X, nullptr, N_SEQ, 512, FFDIM);
  }
  mgemm<1><<<gproj, 256, 0, stream>>>(Xb, PRT, projb, nullptr, out, nullptr, N_SEQ, LLMD, 512);
}

// Round 3
// 524.671 us; speedup vs baseline: 4.1074x; 1.1993x over previous
//
#include <hip/hip_runtime.h>
#include <hip/hip_bf16.h>
#include <math.h>

constexpr int N_SEQ = 8192;
constexpr int D     = 512;
constexpr int NH    = 8;
constexpr int FFDIM = 2048;
constexpr int LLMD  = 4096;
constexpr int NLAYER= 2;

typedef __bf16 bf16x8 __attribute__((ext_vector_type(8)));
typedef float  f32x4  __attribute__((ext_vector_type(4)));
typedef unsigned short u16x8 __attribute__((ext_vector_type(8)));

__device__ __forceinline__ unsigned short f2bf(float x) {
  unsigned u = __builtin_bit_cast(unsigned, x);
  unsigned r = (u + 0x7FFFu + ((u >> 16) & 1u)) >> 16;
  return (unsigned short)r;
}

#define GLOAD16(g, l)                                                        \
  __builtin_amdgcn_global_load_lds(                                          \
      (const __attribute__((address_space(1))) void*)(g),                    \
      (__attribute__((address_space(3))) void*)(l), 16, 0, 0)

// ---------------------------------------------------------------------------
__global__ __launch_bounds__(256) void add_pe_kernel(const float* __restrict__ xin,
                                                     float* __restrict__ xout) {
  int idx = blockIdx.x * 256 + threadIdx.x;
  int d = idx & (D - 1);
  int n = idx >> 9;
  float freq = expf((float)(d & ~1) * (-9.210340371976184f / 512.0f));
  float arg = (float)n * freq;
  float pe = (d & 1) ? cosf(arg) : sinf(arg);
  xout[idx] = xin[idx] + pe;
}

// ---------------------------------------------------------------------------
__global__ __launch_bounds__(256) void ln_bf16(const float* __restrict__ in,
                                               unsigned short* __restrict__ out,
                                               const float* __restrict__ g,
                                               const float* __restrict__ b) {
  int row  = (blockIdx.x * 256 + threadIdx.x) >> 6;
  int lane = threadIdx.x & 63;
  const float* p = in + (size_t)row * D + lane * 8;
  f32x4 v0 = *(const f32x4*)p;
  f32x4 v1 = *(const f32x4*)(p + 4);
  float s  = v0[0] + v0[1] + v0[2] + v0[3] + v1[0] + v1[1] + v1[2] + v1[3];
  float sq = v0[0]*v0[0] + v0[1]*v0[1] + v0[2]*v0[2] + v0[3]*v0[3]
           + v1[0]*v1[0] + v1[1]*v1[1] + v1[2]*v1[2] + v1[3]*v1[3];
#pragma unroll
  for (int o = 32; o > 0; o >>= 1) { s += __shfl_xor(s, o); sq += __shfl_xor(sq, o); }
  float mu  = s * (1.0f / D);
  float var = sq * (1.0f / D) - mu * mu;
  float rs  = rsqrtf(var + 1e-5f);
  f32x4 g0 = *(const f32x4*)(g + lane * 8);
  f32x4 g1 = *(const f32x4*)(g + lane * 8 + 4);
  f32x4 b0 = *(const f32x4*)(b + lane * 8);
  f32x4 b1 = *(const f32x4*)(b + lane * 8 + 4);
  u16x8 r;
#pragma unroll
  for (int i = 0; i < 4; ++i) r[i]     = f2bf((v0[i] - mu) * rs * g0[i] + b0[i]);
#pragma unroll
  for (int i = 0; i < 4; ++i) r[i + 4] = f2bf((v1[i] - mu) * rs * g1[i] + b1[i]);
  *(u16x8*)(out + (size_t)row * D + lane * 8) = r;
}

// ---------------------------------------------------------------------------
// All weight transposes+converts in one kernel. fp32 [K][N] -> bf16 [N][K].
// Segments: [0,2048) QKVO(8 mats 512x512); [2048,4096) W1 (2x 512x2048);
// [4096,6144) W2 (2x 2048x512); [6144,8192) proj (512x4096).
// ---------------------------------------------------------------------------
__global__ __launch_bounds__(256) void wconv_all(const float* __restrict__ Wq,
                                                 const float* __restrict__ Wk,
                                                 const float* __restrict__ Wv,
                                                 const float* __restrict__ Wo,
                                                 const float* __restrict__ W1,
                                                 const float* __restrict__ W2,
                                                 const float* __restrict__ Wp,
                                                 unsigned short* __restrict__ WT) {
  int bid = blockIdx.x;
  const float* src; unsigned short* dst; int K, N, tile;
  if (bid < 2048) {
    int mat = bid >> 8; int w = mat >> 1, l = mat & 1;
    const float* s4 = (w == 0) ? Wq : (w == 1) ? Wk : (w == 2) ? Wv : Wo;
    src = s4 + (size_t)l * 262144;
    dst = WT + ((size_t)l * 4 + w) * 262144;
    K = 512; N = 512; tile = bid & 255;
  } else if (bid < 4096) {
    int b2 = bid - 2048; int l = b2 >> 10;
    src = W1 + (size_t)l * 1048576; dst = WT + 2097152 + (size_t)l * 1048576;
    K = 512; N = 2048; tile = b2 & 1023;
  } else if (bid < 6144) {
    int b2 = bid - 4096; int l = b2 >> 10;
    src = W2 + (size_t)l * 1048576; dst = WT + 4194304 + (size_t)l * 1048576;
    K = 2048; N = 512; tile = b2 & 1023;
  } else {
    src = Wp; dst = WT + 6291456; K = 512; N = 4096; tile = bid - 6144;
  }
  int tilesN = N >> 5;
  int bk = (tile / tilesN) << 5, bn = (tile % tilesN) << 5;
  __shared__ float s[32][33];
  int r = threadIdx.x >> 5, c = threadIdx.x & 31;
#pragma unroll
  for (int i = 0; i < 4; ++i)
    s[r + 8 * i][c] = src[(size_t)(bk + r + 8 * i) * N + bn + c];
  __syncthreads();
#pragma unroll
  for (int i = 0; i < 4; ++i) {
    int rr = r + 8 * i;
    dst[(size_t)(bn + rr) * K + bk + c] = f2bf(s[c][rr]);
  }
}

// ---------------------------------------------------------------------------
// bf16 MFMA GEMM, 2-phase double-buffered (T3 minimum recipe).
// C[M,N] = A[M,K] * Bt[N,K]^T. Tile 128 x BN, BK=32, 256 thr = 4 waves (2x2),
// wave = 64 x BN/2 via 4 x (BN/32) mfma_f32_16x16x32_bf16 fragments.
// FLAGS: 1=bias, 2=GELU, 4=residual, 8=write bf16 Cb, 16=skip fp32 C,
//        32=QKV mode (N=1536: Q-softmax / K raw+colstats / V plain)
// ---------------------------------------------------------------------------
template <int FLAGS, int BN>
__global__ __launch_bounds__(256) void mgemm2(const unsigned short* __restrict__ A,
                                              const unsigned short* __restrict__ Bt,
                                              const float* __restrict__ bias,
                                              const float* __restrict__ res,
                                              float* __restrict__ C,
                                              unsigned short* __restrict__ Cb,
                                              float* __restrict__ C2,
                                              float* __restrict__ C3,
                                              float* __restrict__ pm,
                                              float* __restrict__ ps,
                                              int M, int N, int K) {
  constexpr int WNI = BN / 32;
  __shared__ unsigned short As[2][128][32];
  __shared__ unsigned short Bs[2][BN][32];
  const int tid = threadIdx.x;
  const int lane = tid & 63, wv = tid >> 6;
  const int bm = blockIdx.y * 128, bn = blockIdx.x * BN;
  const int wr = (wv >> 1) * 64, wc = (wv & 1) * (BN / 2);
  f32x4 acc[4][WNI] = {};

  const int srA = wv * 32 + (lane >> 2);
  const int sc  = (lane & 3) * 8;
  const unsigned short* Ap0 = A + (size_t)(bm + srA) * K + sc;
  const unsigned short* Ap1 = Ap0 + (size_t)16 * K;
  const int srB = wv * (BN / 4) + (lane >> 2);
  const unsigned short* Bp0 = Bt + (size_t)(bn + srB) * K + sc;
  const unsigned short* Bp1 = Bp0 + (size_t)16 * K;

  const int kh = (lane >> 4) * 8;
  const int fr = lane & 15;

  auto stage = [&](int b, int k0) {
    GLOAD16(Ap0 + k0, &As[b][srA][sc]);
    GLOAD16(Ap1 + k0, &As[b][srA + 16][sc]);
    GLOAD16(Bp0 + k0, &Bs[b][srB][sc]);
    if constexpr (BN == 128) GLOAD16(Bp1 + k0, &Bs[b][srB + 16][sc]);
  };
  auto compute = [&](const unsigned short (&Asb)[128][32],
                     const unsigned short (&Bsb)[BN][32]) {
    bf16x8 af[4], bfv[WNI];
#pragma unroll
    for (int mi = 0; mi < 4; ++mi)
      af[mi] = *(const bf16x8*)&Asb[wr + mi * 16 + fr][kh];
#pragma unroll
    for (int ni = 0; ni < WNI; ++ni)
      bfv[ni] = *(const bf16x8*)&Bsb[wc + ni * 16 + fr][kh];
#pragma unroll
    for (int mi = 0; mi < 4; ++mi)
#pragma unroll
      for (int ni = 0; ni < WNI; ++ni)
        acc[mi][ni] = __builtin_amdgcn_mfma_f32_16x16x32_bf16(af[mi], bfv[ni], acc[mi][ni], 0, 0, 0);
  };

  const int nt = K >> 5;          // even for all our K (512, 2048)
  stage(0, 0);
  __syncthreads();
  for (int t = 0; t < nt; t += 2) {
    if (t + 1 < nt) stage(1, (t + 1) << 5);
    compute(As[0], Bs[0]);
    __syncthreads();
    if (t + 2 < nt) stage(0, (t + 2) << 5);
    compute(As[1], Bs[1]);
    __syncthreads();
  }

  const int r4 = (lane >> 4) * 4, cc = lane & 15;

  if constexpr (FLAGS & 32) {
    // ------------- fused QKV epilogue (BN==128, N==1536) -------------
    if (bn < 512) {
      // Q: softmax over the head's 64 cols (= this wave's span), * 1/8
#pragma unroll
      for (int mi = 0; mi < 4; ++mi) {
#pragma unroll
        for (int j = 0; j < 4; ++j) {
          float v0 = acc[mi][0][j], v1 = acc[mi][1][j];
          float v2 = acc[mi][2][j], v3 = acc[mi][3][j];
          float m = fmaxf(fmaxf(v0, v1), fmaxf(v2, v3));
          m = fmaxf(m, __shfl_xor(m, 1)); m = fmaxf(m, __shfl_xor(m, 2));
          m = fmaxf(m, __shfl_xor(m, 4)); m = fmaxf(m, __shfl_xor(m, 8));
          float e0 = __expf(v0 - m), e1 = __expf(v1 - m);
          float e2 = __expf(v2 - m), e3 = __expf(v3 - m);
          float s = e0 + e1 + e2 + e3;
          s += __shfl_xor(s, 1); s += __shfl_xor(s, 2);
          s += __shfl_xor(s, 4); s += __shfl_xor(s, 8);
          float w = 0.125f / s;
          int row = bm + wr + mi * 16 + r4 + j;
          float* qr = C + (size_t)row * 512 + bn + wc + cc;
          qr[0] = e0 * w; qr[16] = e1 * w; qr[32] = e2 * w; qr[48] = e3 * w;
        }
      }
    } else if (bn < 1024) {
      // K: raw values + per-(block,wavehalf) column max / sumexp partials
      int colb = bn - 512 + wc + cc;
#pragma unroll
      for (int mi = 0; mi < 4; ++mi)
#pragma unroll
        for (int ni = 0; ni < 4; ++ni) {
          f32x4 v = acc[mi][ni];
#pragma unroll
          for (int j = 0; j < 4; ++j)
            C2[(size_t)(bm + wr + mi * 16 + r4 + j) * 512 + colb + ni * 16] = v[j];
        }
      int prow = blockIdx.y * 2 + (wr ? 1 : 0);
#pragma unroll
      for (int ni = 0; ni < 4; ++ni) {
        float m = -1e30f;
#pragma unroll
        for (int mi = 0; mi < 4; ++mi)
#pragma unroll
          for (int j = 0; j < 4; ++j) m = fmaxf(m, acc[mi][ni][j]);
        m = fmaxf(m, __shfl_xor(m, 16));
        m = fmaxf(m, __shfl_xor(m, 32));
        float s = 0.f;
#pragma unroll
        for (int mi = 0; mi < 4; ++mi)
#pragma unroll
          for (int j = 0; j < 4; ++j) s += __expf(acc[mi][ni][j] - m);
        s += __shfl_xor(s, 16);
        s += __shfl_xor(s, 32);
        if (lane < 16) {
          pm[(size_t)prow * 512 + colb + ni * 16] = m;
          ps[(size_t)prow * 512 + colb + ni * 16] = s;
        }
      }
    } else {
      // V: plain fp32
      int colv = bn - 1024 + wc + cc;
#pragma unroll
      for (int mi = 0; mi < 4; ++mi)
#pragma unroll
        for (int ni = 0; ni < 4; ++ni) {
          f32x4 v = acc[mi][ni];
#pragma unroll
          for (int j = 0; j < 4; ++j)
            C3[(size_t)(bm + wr + mi * 16 + r4 + j) * 512 + colv + ni * 16] = v[j];
        }
    }
  } else {
    // ------------- generic epilogue -------------
#pragma unroll
    for (int mi = 0; mi < 4; ++mi) {
#pragma unroll
      for (int ni = 0; ni < WNI; ++ni) {
        int col = bn + wc + ni * 16 + cc;
        float bsv = (FLAGS & 1) ? bias[col] : 0.0f;
        f32x4 v = acc[mi][ni];
#pragma unroll
        for (int j = 0; j < 4; ++j) {
          int row = bm + wr + mi * 16 + r4 + j;
          float x = v[j] + bsv;
          if (FLAGS & 2) x = 0.5f * x * (1.0f + erff(x * 0.7071067811865475f));
          if (FLAGS & 4) x += res[(size_t)row * N + col];
          if (!(FLAGS & 16)) C[(size_t)row * N + col] = x;
          if (FLAGS & 8) Cb[(size_t)row * N + col] = f2bf(x);
        }
      }
    }
  }
}

// ---------------------------------------------------------------------------
// merge 128 column partials -> cm, ci
// ---------------------------------------------------------------------------
__global__ __launch_bounds__(512) void ksm_merge(const float* __restrict__ pm,
                                                 const float* __restrict__ ps,
                                                 float* __restrict__ cm,
                                                 float* __restrict__ ci) {
  int c = threadIdx.x;
  float m = -1e30f;
#pragma unroll 8
  for (int r = 0; r < 128; ++r) m = fmaxf(m, pm[r * 512 + c]);
  float s = 0.f;
#pragma unroll 8
  for (int r = 0; r < 128; ++r) s += ps[r * 512 + c] * __expf(pm[r * 512 + c] - m);
  cm[c] = m;
  ci[c] = 1.0f / s;
}

// ---------------------------------------------------------------------------
// ctx partials with fused k-normalization: applies exp(k-cm)*ci at stage-in.
// ctx[h][d][e] = sum_n ksm[n,h*64+d]*v[n,h*64+e]; grid (32 chunks, 8 heads).
// ---------------------------------------------------------------------------
__global__ __launch_bounds__(256) void ctx_partial_kernel(const float* __restrict__ k,
                                                          const float* __restrict__ v,
                                                          const float* __restrict__ cm,
                                                          const float* __restrict__ ci,
                                                          float* __restrict__ part) {
  int chunk = blockIdx.x, h = blockIdx.y, t = threadIdx.x;
  __shared__ float ks[64][64], vs[64][64];
  __shared__ float scm[64], sci[64];
  if (t < 64) { scm[t] = cm[h * 64 + t]; sci[t] = ci[h * 64 + t]; }
  float acc[16] = {};
  int e0 = (t >> 6) * 16, dd = t & 63;
  for (int s0 = 0; s0 < 256; s0 += 64) {
    size_t rowbase = (size_t)chunk * 256 + s0;
    __syncthreads();
    for (int i = t; i < 1024; i += 256) {
      int r = i >> 4, c4 = (i & 15) * 4;
      float4 kv = *(const float4*)&k[(rowbase + r) * D + h * 64 + c4];
      kv.x = __expf(kv.x - scm[c4 + 0]) * sci[c4 + 0];
      kv.y = __expf(kv.y - scm[c4 + 1]) * sci[c4 + 1];
      kv.z = __expf(kv.z - scm[c4 + 2]) * sci[c4 + 2];
      kv.w = __expf(kv.w - scm[c4 + 3]) * sci[c4 + 3];
      *(float4*)&ks[r][c4] = kv;
      *(float4*)&vs[r][c4] = *(const float4*)&v[(rowbase + r) * D + h * 64 + c4];
    }
    __syncthreads();
    for (int r = 0; r < 64; ++r) {
      float kd = ks[r][dd];
      float4 v0 = *(const float4*)&vs[r][e0];
      float4 v1 = *(const float4*)&vs[r][e0 + 4];
      float4 v2 = *(const float4*)&vs[r][e0 + 8];
      float4 v3 = *(const float4*)&vs[r][e0 + 12];
      acc[0]  = fmaf(kd, v0.x, acc[0]);  acc[1]  = fmaf(kd, v0.y, acc[1]);
      acc[2]  = fmaf(kd, v0.z, acc[2]);  acc[3]  = fmaf(kd, v0.w, acc[3]);
      acc[4]  = fmaf(kd, v1.x, acc[4]);  acc[5]  = fmaf(kd, v1.y, acc[5]);
      acc[6]  = fmaf(kd, v1.z, acc[6]);  acc[7]  = fmaf(kd, v1.w, acc[7]);
      acc[8]  = fmaf(kd, v2.x, acc[8]);  acc[9]  = fmaf(kd, v2.y, acc[9]);
      acc[10] = fmaf(kd, v2.z, acc[10]); acc[11] = fmaf(kd, v2.w, acc[11]);
      acc[12] = fmaf(kd, v3.x, acc[12]); acc[13] = fmaf(kd, v3.y, acc[13]);
      acc[14] = fmaf(kd, v3.z, acc[14]); acc[15] = fmaf(kd, v3.w, acc[15]);
    }
  }
  float* pb = &part[((size_t)h * 32 + chunk) * 4096 + dd * 64 + e0];
#pragma unroll
  for (int j = 0; j < 16; ++j) pb[j] = acc[j];
}

__global__ __launch_bounds__(256) void ctx_reduce_kernel(const float* __restrict__ part,
                                                         float* __restrict__ ctx) {
  int idx = blockIdx.x * 256 + threadIdx.x;
  int h = idx >> 12, de = idx & 4095;
  float s = 0.f;
#pragma unroll 8
  for (int c = 0; c < 32; ++c) s += part[((size_t)h * 32 + c) * 4096 + de];
  ctx[(size_t)h * 4096 + de] = s;
}

// ---------------------------------------------------------------------------
// o[n, h*64+e] = sum_d q[n,h*64+d] * ctx[h][d][e]  (q pre-softmaxed; bf16 out)
// ---------------------------------------------------------------------------
__global__ __launch_bounds__(256) void attn_o_kernel(const float* __restrict__ q,
                                                     const float* __restrict__ ctx,
                                                     unsigned short* __restrict__ o) {
  int h = blockIdx.y, rc = blockIdx.x, t = threadIdx.x;
  __shared__ float cs[64][64];
  __shared__ float qs[32][64];
  for (int i = t; i < 1024; i += 256) {
    int dd = i >> 4, c4 = (i & 15) * 4;
    *(float4*)&cs[dd][c4] = *(const float4*)&ctx[(size_t)h * 4096 + dd * 64 + c4];
  }
  int rowbase = rc * 32;
  for (int i = t; i < 512; i += 256) {
    int r = i >> 4, c4 = (i & 15) * 4;
    *(float4*)&qs[r][c4] = *(const float4*)&q[(size_t)(rowbase + r) * D + h * 64 + c4];
  }
  __syncthreads();
  int e = t & 63, r0 = (t >> 6) * 8;
  float accv[8] = {};
  for (int dd = 0; dd < 64; ++dd) {
    float ce = cs[dd][e];
#pragma unroll
    for (int i = 0; i < 8; ++i) accv[i] = fmaf(qs[r0 + i][dd], ce, accv[i]);
  }
#pragma unroll
  for (int i = 0; i < 8; ++i)
    o[(size_t)(rowbase + r0 + i) * D + h * 64 + e] = f2bf(accv[i]);
}

// ---------------------------------------------------------------------------
extern "C" void kernel_launch(void* const* d_in, const int* in_sizes, int n_in,
                              void* d_out, int out_size, void* d_ws, size_t ws_size,
                              hipStream_t stream) {
  const float* x_in  = (const float*)d_in[0];
  const float* ln1_g = (const float*)d_in[1];
  const float* ln1_b = (const float*)d_in[2];
  const float* Wq    = (const float*)d_in[3];
  const float* Wk    = (const float*)d_in[4];
  const float* Wv    = (const float*)d_in[5];
  const float* Wo    = (const float*)d_in[6];
  const float* bo    = (const float*)d_in[7];
  const float* ln2_g = (const float*)d_in[8];
  const float* ln2_b = (const float*)d_in[9];
  const float* W1    = (const float*)d_in[10];
  const float* b1    = (const float*)d_in[11];
  const float* W2    = (const float*)d_in[12];
  const float* b2    = (const float*)d_in[13];
  const float* projW = (const float*)d_in[14];
  const float* projb = (const float*)d_in[15];
  float* out = (float*)d_out;
  float* ws  = (float*)d_ws;
  constexpr size_t M1 = 1u << 20;

  float* X    = ws;                       // [0, 4M) floats
  float* Q    = ws + 4 * M1;              // [4M, 8M)
  float* Kb   = ws + 8 * M1;              // [8M, 12M)
  float* V    = ws + 12 * M1;             // [12M, 16M)
  float* CTX  = ws + 16 * M1;             // 32K floats
  float* CTXP = CTX + 32768;              // 1M floats
  float* PM   = CTXP + 1048576;           // 64K floats (128x512)
  float* PS   = PM + 65536;               // 64K
  float* CMAX = PS + 65536;               // 512
  float* CINV = CMAX + 512;               // 512
  unsigned short* Hb  = (unsigned short*)(ws + 18 * M1);  // 4M u16
  unsigned short* O   = (unsigned short*)(ws + 20 * M1);  // 4M u16
  unsigned short* Xb  = O;
  unsigned short* FFH = (unsigned short*)Q;               // 16M u16 overlaps Q,Kb
  unsigned short* WT  = (unsigned short*)(ws + 22 * M1);  // 8M u16

  wconv_all<<<8192, 256, 0, stream>>>(Wq, Wk, Wv, Wo, W1, W2, projW, WT);
  add_pe_kernel<<<(N_SEQ * D) / 256, 256, 0, stream>>>(x_in, X);

  dim3 gqkv(1536 / 128, N_SEQ / 128);
  dim3 g512n(512 / 64, N_SEQ / 128);
  dim3 gff1(FFDIM / 128, N_SEQ / 128);
  dim3 gproj(LLMD / 128, N_SEQ / 128);

  for (int l = 0; l < NLAYER; ++l) {
    const unsigned short* WQKV = WT + (size_t)l * 1048576;
    const unsigned short* WOt  = WQKV + 786432;
    const unsigned short* W1T  = WT + 2097152 + (size_t)l * 1048576;
    const unsigned short* W2T  = WT + 4194304 + (size_t)l * 1048576;

    ln_bf16<<<N_SEQ / 4, 256, 0, stream>>>(X, Hb, ln1_g + l * D, ln1_b + l * D);
    mgemm2<32, 128><<<gqkv, 256, 0, stream>>>(Hb, WQKV, nullptr, nullptr,
                                              Q, nullptr, Kb, V, PM, PS,
                                              N_SEQ, 1536, 512);
    ksm_merge<<<1, 512, 0, stream>>>(PM, PS, CMAX, CINV);
    ctx_partial_kernel<<<dim3(32, NH), 256, 0, stream>>>(Kb, V, CMAX, CINV, CTXP);
    ctx_reduce_kernel<<<(NH * 4096) / 256, 256, 0, stream>>>(CTXP, CTX);
    attn_o_kernel<<<dim3(N_SEQ / 32, NH), 256, 0, stream>>>(Q, CTX, O);
    mgemm2<5, 64><<<g512n, 256, 0, stream>>>(O, WOt, bo + l * D, X, X, nullptr,
                                             nullptr, nullptr, nullptr, nullptr,
                                             N_SEQ, 512, 512);
    ln_bf16<<<N_SEQ / 4, 256, 0, stream>>>(X, Hb, ln2_g + l * D, ln2_b + l * D);
    mgemm2<27, 128><<<gff1, 256, 0, stream>>>(Hb, W1T, b1 + l * FFDIM, nullptr,
                                              nullptr, FFH, nullptr, nullptr,
                                              nullptr, nullptr, N_SEQ, FFDIM, 512);
    if (l == NLAYER - 1)
      mgemm2<13, 64><<<g512n, 256, 0, stream>>>(FFH, W2T, b2 + l * D, X, X, Xb,
                                                nullptr, nullptr, nullptr, nullptr,
                                                N_SEQ, 512, FFDIM);
    else
      mgemm2<5, 64><<<g512n, 256, 0, stream>>>(FFH, W2T, b2 + l * D, X, X, nullptr,
                                               nullptr, nullptr, nullptr, nullptr,
                                               N_SEQ, 512, FFDIM);
  }
  mgemm2<1, 128><<<gproj, 256, 0, stream>>>(Xb, WT + 6291456, projb, nullptr,
                                            out, nullptr, nullptr, nullptr,
                                            nullptr, nullptr, N_SEQ, LLMD, 512);
}